// Round 19
// baseline (248.747 us; speedup 1.0000x reference)
//
#include <hip/hip_runtime.h>

typedef unsigned short u16;
typedef __attribute__((ext_vector_type(4))) unsigned short u16x4;
typedef __attribute__((ext_vector_type(8))) short short8;
typedef __attribute__((ext_vector_type(4))) float f32x4;
typedef __attribute__((ext_vector_type(16))) float f32x16;

#define MFMA32(a, b, c) __builtin_amdgcn_mfma_f32_32x32x16_bf16(a, b, c, 0, 0, 0)

__device__ __forceinline__ u16 f2bf(float f) {
  union { float f; unsigned u; } x; x.f = f;
  unsigned r = x.u + 0x7fffu + ((x.u >> 16) & 1u);
  return (u16)(r >> 16);
}

__device__ __forceinline__ unsigned cvt_pk_bf16(float lo, float hi) {
  unsigned r;
  asm("v_cvt_pk_bf16_f32 %0, %1, %2" : "=v"(r) : "v"(lo), "v"(hi));
  return r;
}

// Schraudolph-style 2^(t-8): bits = trunc(t*2^23 + (119<<23) - 247463).
// +-3% relative; valid t in (-110.9, +60); masked scores use t=-110.
__device__ __forceinline__ float fexp2m8(float t) {
  union { int i; float f; } u;
  u.i = (int)__builtin_fmaf(t, 8388608.f, 997996889.f);
  return u.f;
}

__device__ __forceinline__ void load_lds16(const void* g, void* l) {
  __builtin_amdgcn_global_load_lds(
      (const __attribute__((address_space(1))) void*)g,
      (__attribute__((address_space(3))) void*)l,
      16, 0, 0);
}

// ---------------- fused prep: 4 weight transposes + LN1 (one dispatch) ------
__global__ __launch_bounds__(256) void prep_k(
    const float* __restrict__ wqkv, const float* __restrict__ wproj,
    const float* __restrict__ w1, const float* __restrict__ w2,
    u16* __restrict__ wqkvT, u16* __restrict__ wprojT,
    u16* __restrict__ w1T, u16* __restrict__ w2T,
    const float* __restrict__ x, const float* __restrict__ ln1w,
    const float* __restrict__ ln1b, u16* __restrict__ hbuf) {
  __shared__ float smem[32 * 33];
  const int bid = blockIdx.x;
  const int tid = threadIdx.x;
  if (bid < 6912) {
    const float* in; u16* out; int C, tb;
    int R;
    if (bid < 1728)      { in = wqkv;  out = wqkvT;  R = 768;  C = 2304; tb = bid; }
    else if (bid < 2304) { in = wproj; out = wprojT; R = 768;  C = 768;  tb = bid - 1728; }
    else if (bid < 4608) { in = w1;    out = w1T;    R = 768;  C = 3072; tb = bid - 2304; }
    else                 { in = w2;    out = w2T;    R = 3072; C = 768;  tb = bid - 4608; }
    const int nCt = C >> 5;
    const int c0 = (tb % nCt) * 32, r0 = (tb / nCt) * 32;
    const int tx = tid & 31, ty = tid >> 5;
    float (*tile)[33] = (float(*)[33])smem;
#pragma unroll
    for (int i = 0; i < 4; ++i)
      tile[ty + i * 8][tx] = in[(size_t)(r0 + ty + i * 8) * C + c0 + tx];
    __syncthreads();
#pragma unroll
    for (int i = 0; i < 4; ++i)
      out[(size_t)(c0 + ty + i * 8) * R + r0 + tx] = f2bf(tile[tx][ty + i * 8]);
  } else {
    const int row = bid - 6912;
    const float* xr = x + (size_t)row * 768;
    float v0 = xr[tid], v1 = xr[tid + 256], v2 = xr[tid + 512];
    float s = v0 + v1 + v2;
    float s2 = v0 * v0 + v1 * v1 + v2 * v2;
#pragma unroll
    for (int m = 32; m; m >>= 1) { s += __shfl_xor(s, m); s2 += __shfl_xor(s2, m); }
    float* ps = smem;
    float* ps2 = smem + 4;
    if ((tid & 63) == 0) { ps[tid >> 6] = s; ps2[tid >> 6] = s2; }
    __syncthreads();
    s = ps[0] + ps[1] + ps[2] + ps[3];
    s2 = ps2[0] + ps2[1] + ps2[2] + ps2[3];
    const float mean = s * (1.f / 768.f);
    const float var = s2 * (1.f / 768.f) - mean * mean;
    const float rstd = rsqrtf(var + 1e-5f);
    u16* orow = hbuf + (size_t)row * 768;
    orow[tid]       = f2bf((v0 - mean) * rstd * ln1w[tid]       + ln1b[tid]);
    orow[tid + 256] = f2bf((v1 - mean) * rstd * ln1w[tid + 256] + ln1b[tid + 256]);
    orow[tid + 512] = f2bf((v2 - mean) * rstd * ln1w[tid + 512] + ln1b[tid + 512]);
  }
}

// ---------------- LayerNorm (768) fp32 -> bf16 (LN2) ----------------
__global__ __launch_bounds__(256) void ln_k(const float* __restrict__ X,
                                            const float* __restrict__ w,
                                            const float* __restrict__ b,
                                            u16* __restrict__ O) {
  const int row = blockIdx.x;
  const float* xr = X + (size_t)row * 768;
  const int tid = threadIdx.x;
  float v0 = xr[tid], v1 = xr[tid + 256], v2 = xr[tid + 512];
  float s = v0 + v1 + v2;
  float s2 = v0 * v0 + v1 * v1 + v2 * v2;
#pragma unroll
  for (int m = 32; m; m >>= 1) { s += __shfl_xor(s, m); s2 += __shfl_xor(s2, m); }
  __shared__ float ps[4], ps2[4];
  if ((tid & 63) == 0) { ps[tid >> 6] = s; ps2[tid >> 6] = s2; }
  __syncthreads();
  s = ps[0] + ps[1] + ps[2] + ps[3];
  s2 = ps2[0] + ps2[1] + ps2[2] + ps2[3];
  const float mean = s * (1.f / 768.f);
  const float var = s2 * (1.f / 768.f) - mean * mean;
  const float rstd = rsqrtf(var + 1e-5f);
  u16* orow = O + (size_t)row * 768;
  orow[tid]       = f2bf((v0 - mean) * rstd * w[tid]       + b[tid]);
  orow[tid + 256] = f2bf((v1 - mean) * rstd * w[tid + 256] + b[tid + 256]);
  orow[tid + 512] = f2bf((v2 - mean) * rstd * w[tid + 512] + b[tid + 512]);
}

// ---------------- GEMM: C[M,N] = A[M,K] * Bt[N,K]^T, fused epilogues --------
// r18 covered-drain loop (neutral vs r9 but not worse; kept).
#define BM 128
#define BN 128
#define BKK 64

template <int EPI>
__global__ __launch_bounds__(256, 3) void gemm_k(
    const u16* __restrict__ A, const u16* __restrict__ Bt, int K, int N,
    const float* __restrict__ bias, const float* __restrict__ res,
    float* __restrict__ outF, u16* __restrict__ outB,
    u16* __restrict__ qout, u16* __restrict__ kout, u16* __restrict__ vout) {
  __shared__ __align__(16) u16 sA[BM * BKK];
  __shared__ __align__(16) u16 sB[BN * BKK];
  const int nTn = N / BN;
  const int nwg = gridDim.x;
  const int bid = ((int)blockIdx.x & 7) * (nwg >> 3) + ((int)blockIdx.x >> 3);
  const int tm = bid / nTn, tn = bid % nTn;
  const int m0 = tm * BM, n0 = tn * BN;
  const int tid = threadIdx.x, lane = tid & 63, wv = tid >> 6;
  const int wr = wv >> 1, wc = wv & 1;
  const int fr = lane & 15, fg = lane >> 4;

  const u16* aSrc[4];
  const u16* bSrc[4];
#pragma unroll
  for (int i = 0; i < 4; ++i) {
    int f = (i * 4 + wv) * 64 + lane;
    int r = f >> 3;
    int c = (f & 7) ^ (r & 7);
    aSrc[i] = A + (size_t)(m0 + r) * K + c * 8;
    bSrc[i] = Bt + (size_t)(n0 + r) * K + c * 8;
  }

#define GSTAGE(kt)                                                             \
  do {                                                                         \
    _Pragma("unroll") for (int i_ = 0; i_ < 4; ++i_) {                         \
      load_lds16(aSrc[i_] + (kt), (char*)sA + (i_ * 4 + wv) * 1024);           \
      load_lds16(bSrc[i_] + (kt), (char*)sB + (i_ * 4 + wv) * 1024);           \
    }                                                                          \
  } while (0)

  f32x4 acc[4][4];
#pragma unroll
  for (int m = 0; m < 4; ++m)
#pragma unroll
    for (int n = 0; n < 4; ++n) acc[m][n] = f32x4{0.f, 0.f, 0.f, 0.f};

  const int aswz = fr & 7;
  const int nkt = K / BKK;
  GSTAGE(0);
  __syncthreads();

  for (int t = 0; t < nkt; ++t) {
    short8 af[2][4], bf[2][4];
#pragma unroll
    for (int ks = 0; ks < 2; ++ks) {
      const int c16 = (ks * 4 + fg) ^ aswz;
#pragma unroll
      for (int m = 0; m < 4; ++m)
        af[ks][m] = *(const short8*)((const char*)sA +
                                     (((wr * 64 + m * 16 + fr) * 8 + c16) << 4));
#pragma unroll
      for (int n = 0; n < 4; ++n)
        bf[ks][n] = *(const short8*)((const char*)sB +
                                     (((wc * 64 + n * 16 + fr) * 8 + c16) << 4));
    }
    __syncthreads();
    if (t + 1 < nkt) GSTAGE((t + 1) * BKK);
#pragma unroll
    for (int ks = 0; ks < 2; ++ks)
#pragma unroll
      for (int m = 0; m < 4; ++m)
#pragma unroll
        for (int n = 0; n < 4; ++n)
          acc[m][n] = __builtin_amdgcn_mfma_f32_16x16x32_bf16(af[ks][m], bf[ks][n],
                                                              acc[m][n], 0, 0, 0);
    __syncthreads();
  }
#undef GSTAGE

#pragma unroll
  for (int m = 0; m < 4; ++m) {
    const int row = m0 + wr * 64 + m * 16 + fg * 4;
#pragma unroll
    for (int n = 0; n < 4; ++n) {
      const int col = n0 + wc * 64 + n * 16 + fr;
      f32x4 v = acc[m][n];
      if (EPI == 0) {
        const int part = (col >= 1536) ? 2 : (col >= 768 ? 1 : 0);
        const int cc = col - part * 768;
        const int hh = cc >> 6, dd = cc & 63;
        const int bb = row >> 12;
        const int t = row & 4095;
        const size_t bhh = (size_t)(bb * 12 + hh);
        if (part == 2) {
          // V in per-64-key-chunk subtile layout [16 su][32 d-rows][8 t-elems]
          const int ks_ = (t & 63) >> 4, h_ = (t >> 3) & 1, e0 = t & 7;
          u16x4 pk = {f2bf(v[0]), f2bf(v[1]), f2bf(v[2]), f2bf(v[3])};
          *(u16x4*)(vout + bhh * 262144 + (size_t)(t >> 6) * 4096 +
                    (size_t)(((ks_ << 2) + ((dd >> 5) << 1) + h_) * 256 +
                             (dd & 31) * 8 + e0)) = pk;
        } else if (part == 1) {
          // K in per-64-key-chunk subtile layout [16 su][32 key-rows][8 d-elems]
          const int ks_ = dd >> 4, h_ = (dd >> 3) & 1, e = dd & 7;
          u16* base = kout + bhh * 262144;
#pragma unroll
          for (int r = 0; r < 4; ++r) {
            const int t2 = t + r;
            base[(size_t)(t2 >> 6) * 4096 +
                 (size_t)((((ks_ << 2) + (((t2 & 63) >> 5) << 1) + h_) * 256) +
                          (t2 & 31) * 8 + e)] = f2bf(v[r]);
          }
        } else {
          // Q row-major with folded softmax scale (1/8)*log2(e)
          const float qs = 0.18033688011112042f;
          u16* dst = qout + (bhh * 4096 + t) * 64 + dd;
#pragma unroll
          for (int r = 0; r < 4; ++r) dst[(size_t)r * 64] = f2bf(v[r] * qs);
        }
      } else if (EPI == 1) {
        const float bv = bias[col];
#pragma unroll
        for (int r = 0; r < 4; ++r)
          outF[(size_t)(row + r) * N + col] =
              v[r] + bv + res[(size_t)(row + r) * N + col];
      } else {
        const float bv = bias[col];
#pragma unroll
        for (int r = 0; r < 4; ++r) {
          float t = v[r] + bv;
          float g = 0.5f * t * (1.f + erff(t * 0.70710678118654752f));
          outB[(size_t)(row + r) * N + col] = f2bf(g);
        }
      }
    }
  }
}

// ---------------- GEMM BN=64 variant (proj / MLP2): outF = A*Bt^T+bias+res --
__global__ __launch_bounds__(256, 4) void gemm64_k(
    const u16* __restrict__ A, const u16* __restrict__ Bt, int K, int N,
    const float* __restrict__ bias, const float* __restrict__ res,
    float* __restrict__ outF) {
  __shared__ __align__(16) u16 sA[128 * 64];  // 16KB
  __shared__ __align__(16) u16 sB[64 * 64];   // 8KB
  const int nTn = N / 64;
  const int nwg = gridDim.x;
  const int bid = ((int)blockIdx.x & 7) * (nwg >> 3) + ((int)blockIdx.x >> 3);
  const int tm = bid / nTn, tn = bid % nTn;
  const int m0 = tm * 128, n0 = tn * 64;
  const int tid = threadIdx.x, lane = tid & 63, wv = tid >> 6;
  const int fr = lane & 15, fg = lane >> 4;

  const u16* aSrc[4];
  const u16* bSrc[2];
#pragma unroll
  for (int i = 0; i < 4; ++i) {
    const int f = i * 256 + tid;
    const int r = f >> 3;
    const int c = (f & 7) ^ (r & 7);
    aSrc[i] = A + (size_t)(m0 + r) * K + c * 8;
  }
#pragma unroll
  for (int i = 0; i < 2; ++i) {
    const int f = i * 256 + tid;
    const int r = f >> 3;
    const int c = (f & 7) ^ (r & 7);
    bSrc[i] = Bt + (size_t)(n0 + r) * K + c * 8;
  }

#define GSTAGE64(kt)                                                           \
  do {                                                                         \
    _Pragma("unroll") for (int i_ = 0; i_ < 4; ++i_)                           \
        load_lds16(aSrc[i_] + (kt), (char*)sA + (i_ * 256 + tid) * 16);        \
    _Pragma("unroll") for (int i_ = 0; i_ < 2; ++i_)                           \
        load_lds16(bSrc[i_] + (kt), (char*)sB + (i_ * 256 + tid) * 16);        \
  } while (0)

  f32x4 acc[2][4];
#pragma unroll
  for (int m = 0; m < 2; ++m)
#pragma unroll
    for (int n = 0; n < 4; ++n) acc[m][n] = f32x4{0.f, 0.f, 0.f, 0.f};

  const int aswz = fr & 7;
  const int nkt = K / 64;
  GSTAGE64(0);
  __syncthreads();

  for (int t = 0; t < nkt; ++t) {
    short8 af[2][2], bf[2][4];
#pragma unroll
    for (int ks = 0; ks < 2; ++ks) {
      const int c16 = (ks * 4 + fg) ^ aswz;
#pragma unroll
      for (int m = 0; m < 2; ++m)
        af[ks][m] = *(const short8*)((const char*)sA +
                                     (((wv * 32 + m * 16 + fr) * 8 + c16) << 4));
#pragma unroll
      for (int n = 0; n < 4; ++n)
        bf[ks][n] = *(const short8*)((const char*)sB +
                                     (((n * 16 + fr) * 8 + c16) << 4));
    }
    __syncthreads();
    if (t + 1 < nkt) GSTAGE64((t + 1) * 64);
#pragma unroll
    for (int ks = 0; ks < 2; ++ks)
#pragma unroll
      for (int m = 0; m < 2; ++m)
#pragma unroll
        for (int n = 0; n < 4; ++n)
          acc[m][n] = __builtin_amdgcn_mfma_f32_16x16x32_bf16(af[ks][m], bf[ks][n],
                                                              acc[m][n], 0, 0, 0);
    __syncthreads();
  }
#undef GSTAGE64

#pragma unroll
  for (int m = 0; m < 2; ++m) {
    const int row = m0 + wv * 32 + m * 16 + fg * 4;
#pragma unroll
    for (int n = 0; n < 4; ++n) {
      const int col = n0 + n * 16 + fr;
      const float bv = bias[col];
      f32x4 v = acc[m][n];
#pragma unroll
      for (int r = 0; r < 4; ++r)
        outF[(size_t)(row + r) * N + col] =
            v[r] + bv + res[(size_t)(row + r) * N + col];
    }
  }
}

// ---------------- causal flash attention (swapped-operand, 32x32 MFMA) -----
// r19: diagonal-chunk peeling. For c < qt both halves are fully active and
// unmasked -> main loop merges both halves' QK into one 16-MFMA region with
// 4 independent accumulator chains (issue-bound ~128cy instead of 2x
// dependency-bound 128cy), merged exp/pack, unguarded PV. The diagonal
// chunk (c == qt) keeps the old sequential+masked path. LDS/staging/barrier
// structure identical to r17 (48KB: K dbuf + V single; 3 blocks/CU).
__global__ __launch_bounds__(256, 3) void attn_k(const u16* __restrict__ Q,
                                                 const u16* __restrict__ Kb,
                                                 const u16* __restrict__ Vt,
                                                 u16* __restrict__ Y) {
  __shared__ __align__(16) u16 sK[2][8192];  // 32KB K double buffer
  __shared__ __align__(16) u16 sV[8192];     // 16KB V single buffer
  const int b = blockIdx.x;
  const int c255 = b & 255, slot = b >> 8;
  const int rank = (slot == 0) ? c255 : (slot == 1 ? 511 - c255 : 512 + c255);
  const int qt = 31 - rank / 24;
  const int bh = rank % 24;
  const int bb = bh / 12, hh = bh - bb * 12;
  const int tid = threadIdx.x, lane = tid & 63, wv = tid >> 6;
  const int l31 = lane & 31, hi = lane >> 5;
  const int wq0 = qt * 128 + wv * 32;
  const int qG = wq0 + l31;  // this lane's query row
  const u16* Qh = Q + (size_t)bh * 262144;
  const u16* Kh = Kb + (size_t)bh * 262144;
  const u16* Vh = Vt + (size_t)bh * 262144;

  // Q B-frag (Q^T): lane holds Q[qG][ks*16 + hi*8 .. +7]
  short8 qf[4];
#pragma unroll
  for (int ks = 0; ks < 4; ++ks)
    qf[ks] = *(const short8*)(Qh + (size_t)qG * 64 + ks * 16 + hi * 8);

  // all-ones bf16 A-fragment for the denominator MFMA
  const short8 onesf = {(short)0x3F80, (short)0x3F80, (short)0x3F80,
                        (short)0x3F80, (short)0x3F80, (short)0x3F80,
                        (short)0x3F80, (short)0x3F80};

  f32x16 yacc[2];
  yacc[0] = (f32x16)0.f;
  yacc[1] = (f32x16)0.f;
  f32x16 lsum = (f32x16)0.f;

#define STAGE_K(buf, cc)                                                       \
  do {                                                                         \
    const u16* gk_ = Kh + (size_t)(cc)*8192;                                   \
    _Pragma("unroll") for (int i_ = 0; i_ < 4; ++i_) {                         \
      const int f_ = i_ * 256 + tid;                                           \
      load_lds16(gk_ + f_ * 8, (char*)sK[buf] + f_ * 16);                      \
    }                                                                          \
  } while (0)

#define STAGE_V(cc)                                                            \
  do {                                                                         \
    const u16* gv_ = Vh + (size_t)(cc)*8192;                                   \
    _Pragma("unroll") for (int i_ = 0; i_ < 4; ++i_) {                         \
      const int f_ = i_ * 256 + tid;                                           \
      load_lds16(gv_ + f_ * 8, (char*)sV + f_ * 16);                           \
    }                                                                          \
  } while (0)

  STAGE_K(0, 0);
  __syncthreads();

  const int rdBase = hi * 512 + l31 * 16;  // byte base within a subtile group

  // ---- main loop: c in [0, qt) -- both halves fully active, no mask ----
  for (int c = 0; c < qt; ++c) {
    const int cur = c & 1;
    STAGE_V(c);
    STAGE_K(cur ^ 1, c + 1);  // c+1 <= qt always valid

    // merged QK for both halves: 16 MFMAs, 4 independent chains
    f32x16 s0[2], s1[2];
    s0[0] = (f32x16)0.f; s0[1] = (f32x16)0.f;
    s1[0] = (f32x16)0.f; s1[1] = (f32x16)0.f;
    const char* sK0 = (const char*)sK[cur];
    const char* sK1 = (const char*)sK[cur] + 8192;
    __builtin_amdgcn_s_setprio(1);
#pragma unroll
    for (int ks = 0; ks < 4; ++ks) {
#pragma unroll
      for (int kc = 0; kc < 2; ++kc) {
        short8 kf0 = *(const short8*)(sK0 + ks * 2048 + kc * 1024 + rdBase);
        s0[kc] = MFMA32(kf0, qf[ks], s0[kc]);
        short8 kf1 = *(const short8*)(sK1 + ks * 2048 + kc * 1024 + rdBase);
        s1[kc] = MFMA32(kf1, qf[ks], s1[kc]);
      }
    }
    __builtin_amdgcn_s_setprio(0);

    // merged exp
#pragma unroll
    for (int kc = 0; kc < 2; ++kc)
#pragma unroll
      for (int r = 0; r < 16; ++r) {
        s0[kc][r] = fexp2m8(s0[kc][r]);
        s1[kc][r] = fexp2m8(s1[kc][r]);
      }

    // merged pack into pw[2][16]
    unsigned pw[2][16];
#pragma unroll
    for (int hf = 0; hf < 2; ++hf) {
#pragma unroll
      for (int ks2 = 0; ks2 < 4; ++ks2) {
        const int kc = ks2 >> 1, rb = (ks2 & 1) * 8;
        const f32x16* sp = (hf == 0) ? s0 : s1;
        unsigned W0 = cvt_pk_bf16(sp[kc][rb + 0], sp[kc][rb + 1]);
        unsigned W1 = cvt_pk_bf16(sp[kc][rb + 2], sp[kc][rb + 3]);
        unsigned W2 = cvt_pk_bf16(sp[kc][rb + 4], sp[kc][rb + 5]);
        unsigned W3 = cvt_pk_bf16(sp[kc][rb + 6], sp[kc][rb + 7]);
        asm("v_permlane32_swap_b32 %0, %1" : "+v"(W0), "+v"(W2));
        asm("v_permlane32_swap_b32 %0, %1" : "+v"(W1), "+v"(W3));
        pw[hf][ks2 * 4 + 0] = W0;
        pw[hf][ks2 * 4 + 1] = W1;
        pw[hf][ks2 * 4 + 2] = W2;
        pw[hf][ks2 * 4 + 3] = W3;
      }
    }

    __syncthreads();  // drains V(c) + K(c+1) staging (covered by compute)

    // PV both halves, unguarded
    __builtin_amdgcn_s_setprio(1);
#pragma unroll
    for (int hf = 0; hf < 2; ++hf) {
      const char* sVb = (const char*)sV + hf * 8192;
#pragma unroll
      for (int ks2 = 0; ks2 < 4; ++ks2) {
        union { unsigned w[4]; short8 v; } pb;
        pb.w[0] = pw[hf][ks2 * 4 + 0];
        pb.w[1] = pw[hf][ks2 * 4 + 1];
        pb.w[2] = pw[hf][ks2 * 4 + 2];
        pb.w[3] = pw[hf][ks2 * 4 + 3];
#pragma unroll
        for (int dt = 0; dt < 2; ++dt) {
          short8 vf = *(const short8*)(sVb + ks2 * 2048 + dt * 1024 + rdBase);
          yacc[dt] = MFMA32(vf, pb.v, yacc[dt]);
        }
        lsum = MFMA32(onesf, pb.v, lsum);
      }
    }
    __builtin_amdgcn_s_setprio(0);
    __syncthreads();  // pure LDS reuse fence
  }

  // ---- peeled diagonal chunk c == qt: sequential halves with mask ----
  {
    const int c = qt, cur = qt & 1;
    STAGE_V(c);
    const bool act1 = (c * 128 + 64) <= (wq0 + 31);  // wv >= 2

    unsigned pw[2][16];
#pragma unroll
    for (int hf = 0; hf < 2; ++hf) {
      if (hf == 0 || act1) {
        const int kb = c * 128 + hf * 64;
        const char* sKb = (const char*)sK[cur] + hf * 8192;

        f32x16 s[2];
        s[0] = (f32x16)0.f;
        s[1] = (f32x16)0.f;
        __builtin_amdgcn_s_setprio(1);
#pragma unroll
        for (int ks = 0; ks < 4; ++ks) {
#pragma unroll
          for (int kc = 0; kc < 2; ++kc) {
            short8 kf = *(const short8*)(sKb + ks * 2048 + kc * 1024 + rdBase);
            s[kc] = MFMA32(kf, qf[ks], s[kc]);
          }
        }
        __builtin_amdgcn_s_setprio(0);

        // causal mask (always boundary here)
#pragma unroll
        for (int kc = 0; kc < 2; ++kc)
#pragma unroll
          for (int r = 0; r < 16; ++r) {
            const int key = kb + kc * 32 + (r & 3) + 8 * (r >> 2) + 4 * hi;
            if (key > qG) s[kc][r] = -110.f;
          }

#pragma unroll
        for (int kc = 0; kc < 2; ++kc)
#pragma unroll
          for (int r = 0; r < 16; ++r)
            s[kc][r] = fexp2m8(s[kc][r]);

#pragma unroll
        for (int ks2 = 0; ks2 < 4; ++ks2) {
          const int kc = ks2 >> 1, rb = (ks2 & 1) * 8;
          unsigned W0 = cvt_pk_bf16(s[kc][rb + 0], s[kc][rb + 1]);
          unsigned W1 = cvt_pk_bf16(s[kc][rb + 2], s[kc][rb + 3]);
          unsigned W2 = cvt_pk_bf16(s[kc][rb + 4], s[kc][rb + 5]);
          unsigned W3 = cvt_pk_bf16(s[kc][rb + 6], s[kc][rb + 7]);
          asm("v_permlane32_swap_b32 %0, %1" : "+v"(W0), "+v"(W2));
          asm("v_permlane32_swap_b32 %0, %1" : "+v"(W1), "+v"(W3));
          pw[hf][ks2 * 4 + 0] = W0;
          pw[hf][ks2 * 4 + 1] = W1;
          pw[hf][ks2 * 4 + 2] = W2;
          pw[hf][ks2 * 4 + 3] = W3;
        }
      }
    }

    __syncthreads();  // drains V(qt) staging

#pragma unroll
    for (int hf = 0; hf < 2; ++hf) {
      if (hf == 0 || act1) {
        const char* sVb = (const char*)sV + hf * 8192;
        __builtin_amdgcn_s_setprio(1);
#pragma unroll
        for (int ks2 = 0; ks2 < 4; ++ks2) {
          union { unsigned w[4]; short8 v; } pb;
          pb.w[0] = pw[hf][ks2 * 4 + 0];
          pb.w[1] = pw[hf][ks2 * 4 + 1];
          pb.w[2] = pw[hf][ks2 * 4 + 2];
          pb.w[3] = pw[hf][ks2 * 4 + 3];
#pragma unroll
          for (int dt = 0; dt < 2; ++dt) {
            short8 vf = *(const short8*)(sVb + ks2 * 2048 + dt * 1024 + rdBase);
            yacc[dt] = MFMA32(vf, pb.v, yacc[dt]);
          }
          lsum = MFMA32(onesf, pb.v, lsum);
        }
        __builtin_amdgcn_s_setprio(0);
      }
    }
  }

  // ---- epilogue: y[q][d], q = lane&31, d = dt*32 + (r&3)+8*(r>>2)+4*hi ----
  const float inv = 1.f / lsum[0];
  u16* Yr = Y + (size_t)(bb * 4096 + qt * 128 + wv * 32 + l31) * 768 + hh * 64;
#pragma unroll
  for (int dt = 0; dt < 2; ++dt)
#pragma unroll
    for (int g = 0; g < 4; ++g) {
      u16x4 pk = {f2bf(yacc[dt][g * 4 + 0] * inv), f2bf(yacc[dt][g * 4 + 1] * inv),
                  f2bf(yacc[dt][g * 4 + 2] * inv), f2bf(yacc[dt][g * 4 + 3] * inv)};
      *(u16x4*)(Yr + dt * 32 + g * 8 + hi * 4) = pk;
    }
#undef STAGE_K
#undef STAGE_V
}

// ---------------- host ----------------
extern "C" void kernel_launch(void* const* d_in, const int* in_sizes, int n_in,
                              void* d_out, int out_size, void* d_ws, size_t ws_size,
                              hipStream_t stream) {
  const float* x = (const float*)d_in[0];
  const float* ln1w = (const float*)d_in[1];
  const float* ln1b = (const float*)d_in[2];
  const float* wqkv = (const float*)d_in[3];
  const float* wproj = (const float*)d_in[4];
  const float* bproj = (const float*)d_in[5];
  const float* ln2w = (const float*)d_in[6];
  const float* ln2b = (const float*)d_in[7];
  const float* w1 = (const float*)d_in[8];
  const float* b1 = (const float*)d_in[9];
  const float* w2 = (const float*)d_in[10];
  const float* b2 = (const float*)d_in[11];
  float* out = (float*)d_out;
  char* ws = (char*)d_ws;

  const size_t SZ_ACT = (size_t)8192 * 768 * 2;
  u16* hbuf = (u16*)(ws);
  u16* qb = (u16*)(ws + SZ_ACT);
  u16* kb = (u16*)(ws + 2 * SZ_ACT);
  u16* vT = (u16*)(ws + 3 * SZ_ACT);
  u16* ybuf = (u16*)(ws + 4 * SZ_ACT);
  float* out1 = (float*)(ws + 5 * SZ_ACT);
  char* wsw = ws + 5 * SZ_ACT + (size_t)8192 * 768 * 4;
  u16* wqkvT = (u16*)(wsw);
  u16* wprojT = (u16*)(wsw + 3538944);
  u16* w1T = (u16*)(wsw + 3538944 + 1179648);
  u16* w2T = (u16*)(wsw + 3538944 + 1179648 + 4718592);
  u16* h3 = hbuf;
  u16* h2 = ybuf;

  prep_k<<<15104, 256, 0, stream>>>(wqkv, wproj, w1, w2,
                                    wqkvT, wprojT, w1T, w2T,
                                    x, ln1w, ln1b, hbuf);

  gemm_k<0><<<64 * (2304 / 128), 256, 0, stream>>>(hbuf, wqkvT, 768, 2304,
      nullptr, nullptr, nullptr, nullptr, qb, kb, vT);

  attn_k<<<768, 256, 0, stream>>>(qb, kb, vT, ybuf);

  gemm64_k<<<64 * (768 / 64), 256, 0, stream>>>(ybuf, wprojT, 768, 768,
      bproj, x, out1);

  ln_k<<<8192, 256, 0, stream>>>(out1, ln2w, ln2b, h2);

  gemm_k<2><<<64 * (3072 / 128), 256, 0, stream>>>(h2, w1T, 768, 3072,
      b1, nullptr, nullptr, h3, nullptr, nullptr, nullptr);

  gemm64_k<<<64 * (768 / 64), 256, 0, stream>>>(h3, w2T, 3072, 768,
      b2, out1, out);

  (void)in_sizes; (void)n_in; (void)out_size; (void)ws_size;
}

// Round 20
// 243.383 us; speedup vs baseline: 1.0220x; 1.0220x over previous
//
#include <hip/hip_runtime.h>

typedef unsigned short u16;
typedef __attribute__((ext_vector_type(4))) unsigned short u16x4;
typedef __attribute__((ext_vector_type(8))) short short8;
typedef __attribute__((ext_vector_type(4))) float f32x4;
typedef __attribute__((ext_vector_type(16))) float f32x16;

#define MFMA32(a, b, c) __builtin_amdgcn_mfma_f32_32x32x16_bf16(a, b, c, 0, 0, 0)

__device__ __forceinline__ u16 f2bf(float f) {
  union { float f; unsigned u; } x; x.f = f;
  unsigned r = x.u + 0x7fffu + ((x.u >> 16) & 1u);
  return (u16)(r >> 16);
}

__device__ __forceinline__ float bf2f(u16 v) {
  union { unsigned u; float f; } x; x.u = ((unsigned)v) << 16;
  return x.f;
}

__device__ __forceinline__ unsigned cvt_pk_bf16(float lo, float hi) {
  unsigned r;
  asm("v_cvt_pk_bf16_f32 %0, %1, %2" : "=v"(r) : "v"(lo), "v"(hi));
  return r;
}

// Schraudolph-style 2^(t-8): bits = trunc(t*2^23 + (119<<23) - 247463).
// +-3% relative; valid t in (-110.9, +60); masked scores use t=-110.
__device__ __forceinline__ float fexp2m8(float t) {
  union { int i; float f; } u;
  u.i = (int)__builtin_fmaf(t, 8388608.f, 997996889.f);
  return u.f;
}

__device__ __forceinline__ void load_lds16(const void* g, void* l) {
  __builtin_amdgcn_global_load_lds(
      (const __attribute__((address_space(1))) void*)g,
      (__attribute__((address_space(3))) void*)l,
      16, 0, 0);
}

// ---------------- fused prep: 4 weight transposes + LN1 (one dispatch) ------
__global__ __launch_bounds__(256) void prep_k(
    const float* __restrict__ wqkv, const float* __restrict__ wproj,
    const float* __restrict__ w1, const float* __restrict__ w2,
    u16* __restrict__ wqkvT, u16* __restrict__ wprojT,
    u16* __restrict__ w1T, u16* __restrict__ w2T,
    const float* __restrict__ x, const float* __restrict__ ln1w,
    const float* __restrict__ ln1b, u16* __restrict__ hbuf) {
  __shared__ float smem[32 * 33];
  const int bid = blockIdx.x;
  const int tid = threadIdx.x;
  if (bid < 6912) {
    const float* in; u16* out; int C, tb;
    int R;
    if (bid < 1728)      { in = wqkv;  out = wqkvT;  R = 768;  C = 2304; tb = bid; }
    else if (bid < 2304) { in = wproj; out = wprojT; R = 768;  C = 768;  tb = bid - 1728; }
    else if (bid < 4608) { in = w1;    out = w1T;    R = 768;  C = 3072; tb = bid - 2304; }
    else                 { in = w2;    out = w2T;    R = 3072; C = 768;  tb = bid - 4608; }
    const int nCt = C >> 5;
    const int c0 = (tb % nCt) * 32, r0 = (tb / nCt) * 32;
    const int tx = tid & 31, ty = tid >> 5;
    float (*tile)[33] = (float(*)[33])smem;
#pragma unroll
    for (int i = 0; i < 4; ++i)
      tile[ty + i * 8][tx] = in[(size_t)(r0 + ty + i * 8) * C + c0 + tx];
    __syncthreads();
#pragma unroll
    for (int i = 0; i < 4; ++i)
      out[(size_t)(c0 + ty + i * 8) * R + r0 + tx] = f2bf(tile[tx][ty + i * 8]);
  } else {
    const int row = bid - 6912;
    const float* xr = x + (size_t)row * 768;
    float v0 = xr[tid], v1 = xr[tid + 256], v2 = xr[tid + 512];
    float s = v0 + v1 + v2;
    float s2 = v0 * v0 + v1 * v1 + v2 * v2;
#pragma unroll
    for (int m = 32; m; m >>= 1) { s += __shfl_xor(s, m); s2 += __shfl_xor(s2, m); }
    float* ps = smem;
    float* ps2 = smem + 4;
    if ((tid & 63) == 0) { ps[tid >> 6] = s; ps2[tid >> 6] = s2; }
    __syncthreads();
    s = ps[0] + ps[1] + ps[2] + ps[3];
    s2 = ps2[0] + ps2[1] + ps2[2] + ps2[3];
    const float mean = s * (1.f / 768.f);
    const float var = s2 * (1.f / 768.f) - mean * mean;
    const float rstd = rsqrtf(var + 1e-5f);
    u16* orow = hbuf + (size_t)row * 768;
    orow[tid]       = f2bf((v0 - mean) * rstd * ln1w[tid]       + ln1b[tid]);
    orow[tid + 256] = f2bf((v1 - mean) * rstd * ln1w[tid + 256] + ln1b[tid + 256]);
    orow[tid + 512] = f2bf((v2 - mean) * rstd * ln1w[tid + 512] + ln1b[tid + 512]);
  }
}

// ---------------- LayerNorm (768) bf16 -> bf16 (LN2, reads bf16 residual) ---
__global__ __launch_bounds__(256) void ln_k(const u16* __restrict__ X,
                                            const float* __restrict__ w,
                                            const float* __restrict__ b,
                                            u16* __restrict__ O) {
  const int row = blockIdx.x;
  const u16* xr = X + (size_t)row * 768;
  const int tid = threadIdx.x;
  float v0 = bf2f(xr[tid]), v1 = bf2f(xr[tid + 256]), v2 = bf2f(xr[tid + 512]);
  float s = v0 + v1 + v2;
  float s2 = v0 * v0 + v1 * v1 + v2 * v2;
#pragma unroll
  for (int m = 32; m; m >>= 1) { s += __shfl_xor(s, m); s2 += __shfl_xor(s2, m); }
  __shared__ float ps[4], ps2[4];
  if ((tid & 63) == 0) { ps[tid >> 6] = s; ps2[tid >> 6] = s2; }
  __syncthreads();
  s = ps[0] + ps[1] + ps[2] + ps[3];
  s2 = ps2[0] + ps2[1] + ps2[2] + ps2[3];
  const float mean = s * (1.f / 768.f);
  const float var = s2 * (1.f / 768.f) - mean * mean;
  const float rstd = rsqrtf(var + 1e-5f);
  u16* orow = O + (size_t)row * 768;
  orow[tid]       = f2bf((v0 - mean) * rstd * w[tid]       + b[tid]);
  orow[tid + 256] = f2bf((v1 - mean) * rstd * w[tid + 256] + b[tid + 256]);
  orow[tid + 512] = f2bf((v2 - mean) * rstd * w[tid + 512] + b[tid + 512]);
}

// ---------------- GEMM: C[M,N] = A[M,K] * Bt[N,K]^T, fused epilogues --------
// r18 covered-drain loop.
#define BM 128
#define BN 128
#define BKK 64

template <int EPI>
__global__ __launch_bounds__(256, 3) void gemm_k(
    const u16* __restrict__ A, const u16* __restrict__ Bt, int K, int N,
    const float* __restrict__ bias, const float* __restrict__ res,
    float* __restrict__ outF, u16* __restrict__ outB,
    u16* __restrict__ qout, u16* __restrict__ kout, u16* __restrict__ vout) {
  __shared__ __align__(16) u16 sA[BM * BKK];
  __shared__ __align__(16) u16 sB[BN * BKK];
  const int nTn = N / BN;
  const int nwg = gridDim.x;
  const int bid = ((int)blockIdx.x & 7) * (nwg >> 3) + ((int)blockIdx.x >> 3);
  const int tm = bid / nTn, tn = bid % nTn;
  const int m0 = tm * BM, n0 = tn * BN;
  const int tid = threadIdx.x, lane = tid & 63, wv = tid >> 6;
  const int wr = wv >> 1, wc = wv & 1;
  const int fr = lane & 15, fg = lane >> 4;

  const u16* aSrc[4];
  const u16* bSrc[4];
#pragma unroll
  for (int i = 0; i < 4; ++i) {
    int f = (i * 4 + wv) * 64 + lane;
    int r = f >> 3;
    int c = (f & 7) ^ (r & 7);
    aSrc[i] = A + (size_t)(m0 + r) * K + c * 8;
    bSrc[i] = Bt + (size_t)(n0 + r) * K + c * 8;
  }

#define GSTAGE(kt)                                                             \
  do {                                                                         \
    _Pragma("unroll") for (int i_ = 0; i_ < 4; ++i_) {                         \
      load_lds16(aSrc[i_] + (kt), (char*)sA + (i_ * 4 + wv) * 1024);           \
      load_lds16(bSrc[i_] + (kt), (char*)sB + (i_ * 4 + wv) * 1024);           \
    }                                                                          \
  } while (0)

  f32x4 acc[4][4];
#pragma unroll
  for (int m = 0; m < 4; ++m)
#pragma unroll
    for (int n = 0; n < 4; ++n) acc[m][n] = f32x4{0.f, 0.f, 0.f, 0.f};

  const int aswz = fr & 7;
  const int nkt = K / BKK;
  GSTAGE(0);
  __syncthreads();

  for (int t = 0; t < nkt; ++t) {
    short8 af[2][4], bf[2][4];
#pragma unroll
    for (int ks = 0; ks < 2; ++ks) {
      const int c16 = (ks * 4 + fg) ^ aswz;
#pragma unroll
      for (int m = 0; m < 4; ++m)
        af[ks][m] = *(const short8*)((const char*)sA +
                                     (((wr * 64 + m * 16 + fr) * 8 + c16) << 4));
#pragma unroll
      for (int n = 0; n < 4; ++n)
        bf[ks][n] = *(const short8*)((const char*)sB +
                                     (((wc * 64 + n * 16 + fr) * 8 + c16) << 4));
    }
    __syncthreads();
    if (t + 1 < nkt) GSTAGE((t + 1) * BKK);
#pragma unroll
    for (int ks = 0; ks < 2; ++ks)
#pragma unroll
      for (int m = 0; m < 4; ++m)
#pragma unroll
        for (int n = 0; n < 4; ++n)
          acc[m][n] = __builtin_amdgcn_mfma_f32_16x16x32_bf16(af[ks][m], bf[ks][n],
                                                              acc[m][n], 0, 0, 0);
    __syncthreads();
  }
#undef GSTAGE

#pragma unroll
  for (int m = 0; m < 4; ++m) {
    const int row = m0 + wr * 64 + m * 16 + fg * 4;
#pragma unroll
    for (int n = 0; n < 4; ++n) {
      const int col = n0 + wc * 64 + n * 16 + fr;
      f32x4 v = acc[m][n];
      if (EPI == 0) {
        const int part = (col >= 1536) ? 2 : (col >= 768 ? 1 : 0);
        const int cc = col - part * 768;
        const int hh = cc >> 6, dd = cc & 63;
        const int bb = row >> 12;
        const int t = row & 4095;
        const size_t bhh = (size_t)(bb * 12 + hh);
        if (part == 2) {
          // V in per-64-key-chunk subtile layout [16 su][32 d-rows][8 t-elems]
          const int ks_ = (t & 63) >> 4, h_ = (t >> 3) & 1, e0 = t & 7;
          u16x4 pk = {f2bf(v[0]), f2bf(v[1]), f2bf(v[2]), f2bf(v[3])};
          *(u16x4*)(vout + bhh * 262144 + (size_t)(t >> 6) * 4096 +
                    (size_t)(((ks_ << 2) + ((dd >> 5) << 1) + h_) * 256 +
                             (dd & 31) * 8 + e0)) = pk;
        } else if (part == 1) {
          // K in per-64-key-chunk subtile layout [16 su][32 key-rows][8 d-elems]
          const int ks_ = dd >> 4, h_ = (dd >> 3) & 1, e = dd & 7;
          u16* base = kout + bhh * 262144;
#pragma unroll
          for (int r = 0; r < 4; ++r) {
            const int t2 = t + r;
            base[(size_t)(t2 >> 6) * 4096 +
                 (size_t)((((ks_ << 2) + (((t2 & 63) >> 5) << 1) + h_) * 256) +
                          (t2 & 31) * 8 + e)] = f2bf(v[r]);
          }
        } else {
          // Q row-major with folded softmax scale (1/8)*log2(e)
          const float qs = 0.18033688011112042f;
          u16* dst = qout + (bhh * 4096 + t) * 64 + dd;
#pragma unroll
          for (int r = 0; r < 4; ++r) dst[(size_t)r * 64] = f2bf(v[r] * qs);
        }
      } else {
        const float bv = bias[col];
#pragma unroll
        for (int r = 0; r < 4; ++r) {
          float t = v[r] + bv;
          float g = 0.5f * t * (1.f + erff(t * 0.70710678118654752f));
          outB[(size_t)(row + r) * N + col] = f2bf(g);
        }
      }
    }
  }
}

// ---------------- GEMM BN=64 variant (proj / MLP2) --------------------------
// MODE 0 (proj): res = fp32 x, out = bf16 out1b (residual stream stored bf16)
// MODE 1 (MLP2): res = bf16 out1b, out = fp32 d_out
template <int MODE>
__global__ __launch_bounds__(256, 4) void gemm64_k(
    const u16* __restrict__ A, const u16* __restrict__ Bt, int K, int N,
    const float* __restrict__ bias, const float* __restrict__ resF,
    const u16* __restrict__ resB, float* __restrict__ outF,
    u16* __restrict__ outB) {
  __shared__ __align__(16) u16 sA[128 * 64];  // 16KB
  __shared__ __align__(16) u16 sB[64 * 64];   // 8KB
  const int nTn = N / 64;
  const int nwg = gridDim.x;
  const int bid = ((int)blockIdx.x & 7) * (nwg >> 3) + ((int)blockIdx.x >> 3);
  const int tm = bid / nTn, tn = bid % nTn;
  const int m0 = tm * 128, n0 = tn * 64;
  const int tid = threadIdx.x, lane = tid & 63, wv = tid >> 6;
  const int fr = lane & 15, fg = lane >> 4;

  const u16* aSrc[4];
  const u16* bSrc[2];
#pragma unroll
  for (int i = 0; i < 4; ++i) {
    const int f = i * 256 + tid;
    const int r = f >> 3;
    const int c = (f & 7) ^ (r & 7);
    aSrc[i] = A + (size_t)(m0 + r) * K + c * 8;
  }
#pragma unroll
  for (int i = 0; i < 2; ++i) {
    const int f = i * 256 + tid;
    const int r = f >> 3;
    const int c = (f & 7) ^ (r & 7);
    bSrc[i] = Bt + (size_t)(n0 + r) * K + c * 8;
  }

#define GSTAGE64(kt)                                                           \
  do {                                                                         \
    _Pragma("unroll") for (int i_ = 0; i_ < 4; ++i_)                           \
        load_lds16(aSrc[i_] + (kt), (char*)sA + (i_ * 256 + tid) * 16);        \
    _Pragma("unroll") for (int i_ = 0; i_ < 2; ++i_)                           \
        load_lds16(bSrc[i_] + (kt), (char*)sB + (i_ * 256 + tid) * 16);        \
  } while (0)

  f32x4 acc[2][4];
#pragma unroll
  for (int m = 0; m < 2; ++m)
#pragma unroll
    for (int n = 0; n < 4; ++n) acc[m][n] = f32x4{0.f, 0.f, 0.f, 0.f};

  const int aswz = fr & 7;
  const int nkt = K / 64;
  GSTAGE64(0);
  __syncthreads();

  for (int t = 0; t < nkt; ++t) {
    short8 af[2][2], bf[2][4];
#pragma unroll
    for (int ks = 0; ks < 2; ++ks) {
      const int c16 = (ks * 4 + fg) ^ aswz;
#pragma unroll
      for (int m = 0; m < 2; ++m)
        af[ks][m] = *(const short8*)((const char*)sA +
                                     (((wv * 32 + m * 16 + fr) * 8 + c16) << 4));
#pragma unroll
      for (int n = 0; n < 4; ++n)
        bf[ks][n] = *(const short8*)((const char*)sB +
                                     (((n * 16 + fr) * 8 + c16) << 4));
    }
    __syncthreads();
    if (t + 1 < nkt) GSTAGE64((t + 1) * 64);
#pragma unroll
    for (int ks = 0; ks < 2; ++ks)
#pragma unroll
      for (int m = 0; m < 2; ++m)
#pragma unroll
        for (int n = 0; n < 4; ++n)
          acc[m][n] = __builtin_amdgcn_mfma_f32_16x16x32_bf16(af[ks][m], bf[ks][n],
                                                              acc[m][n], 0, 0, 0);
    __syncthreads();
  }
#undef GSTAGE64

#pragma unroll
  for (int m = 0; m < 2; ++m) {
    const int row = m0 + wv * 32 + m * 16 + fg * 4;
#pragma unroll
    for (int n = 0; n < 4; ++n) {
      const int col = n0 + n * 16 + fr;
      const float bv = bias[col];
      f32x4 v = acc[m][n];
#pragma unroll
      for (int r = 0; r < 4; ++r) {
        if (MODE == 0) {
          const float t = v[r] + bv + resF[(size_t)(row + r) * N + col];
          outB[(size_t)(row + r) * N + col] = f2bf(t);
        } else {
          outF[(size_t)(row + r) * N + col] =
              v[r] + bv + bf2f(resB[(size_t)(row + r) * N + col]);
        }
      }
    }
  }
}

// ---------------- causal flash attention (swapped-operand, 32x32 MFMA) -----
// r17/r18 proven (72.7us): LDS = K dbuf (32KB) + V single (16KB) = 48KB ->
// 3 blocks/CU, all 768 blocks co-resident. Per chunk: STAGE_V(c)+STAGE_K(c+1)
// -> QK+softmax+pack both halves (P packed in regs) -> mid-barrier (only
// vmcnt drain, covered) -> PV both halves -> end fence. Balanced rank remap
// {c,511-c,512+c}; fast-exp2; ones-row-MFMA denominator. (r19's merged-half
// ILP variant regressed; reverted.)
__global__ __launch_bounds__(256, 3) void attn_k(const u16* __restrict__ Q,
                                                 const u16* __restrict__ Kb,
                                                 const u16* __restrict__ Vt,
                                                 u16* __restrict__ Y) {
  __shared__ __align__(16) u16 sK[2][8192];  // 32KB K double buffer
  __shared__ __align__(16) u16 sV[8192];     // 16KB V single buffer
  const int b = blockIdx.x;
  const int c255 = b & 255, slot = b >> 8;
  const int rank = (slot == 0) ? c255 : (slot == 1 ? 511 - c255 : 512 + c255);
  const int qt = 31 - rank / 24;
  const int bh = rank % 24;
  const int bb = bh / 12, hh = bh - bb * 12;
  const int tid = threadIdx.x, lane = tid & 63, wv = tid >> 6;
  const int l31 = lane & 31, hi = lane >> 5;
  const int wq0 = qt * 128 + wv * 32;
  const int qG = wq0 + l31;  // this lane's query row
  const u16* Qh = Q + (size_t)bh * 262144;
  const u16* Kh = Kb + (size_t)bh * 262144;
  const u16* Vh = Vt + (size_t)bh * 262144;

  // Q B-frag (Q^T): lane holds Q[qG][ks*16 + hi*8 .. +7]
  short8 qf[4];
#pragma unroll
  for (int ks = 0; ks < 4; ++ks)
    qf[ks] = *(const short8*)(Qh + (size_t)qG * 64 + ks * 16 + hi * 8);

  // all-ones bf16 A-fragment for the denominator MFMA
  const short8 onesf = {(short)0x3F80, (short)0x3F80, (short)0x3F80,
                        (short)0x3F80, (short)0x3F80, (short)0x3F80,
                        (short)0x3F80, (short)0x3F80};

  f32x16 yacc[2];
  yacc[0] = (f32x16)0.f;
  yacc[1] = (f32x16)0.f;
  f32x16 lsum = (f32x16)0.f;

#define STAGE_K(buf, cc)                                                       \
  do {                                                                         \
    const u16* gk_ = Kh + (size_t)(cc)*8192;                                   \
    _Pragma("unroll") for (int i_ = 0; i_ < 4; ++i_) {                         \
      const int f_ = i_ * 256 + tid;                                           \
      load_lds16(gk_ + f_ * 8, (char*)sK[buf] + f_ * 16);                      \
    }                                                                          \
  } while (0)

#define STAGE_V(cc)                                                            \
  do {                                                                         \
    const u16* gv_ = Vh + (size_t)(cc)*8192;                                   \
    _Pragma("unroll") for (int i_ = 0; i_ < 4; ++i_) {                         \
      const int f_ = i_ * 256 + tid;                                           \
      load_lds16(gv_ + f_ * 8, (char*)sV + f_ * 16);                           \
    }                                                                          \
  } while (0)

  const int nch = qt + 1;  // 128-key chunks
  STAGE_K(0, 0);
  __syncthreads();

  const int rdBase = hi * 512 + l31 * 16;  // byte base within a subtile group

  for (int c = 0; c < nch; ++c) {
    const int cur = c & 1;
    STAGE_V(c);                              // V(c) lands before mid-barrier
    if (c + 1 < nch) STAGE_K(cur ^ 1, c + 1);

    // half1 active? (half0 always active: c*128 <= wq0+31 for all c <= qt)
    const bool act1 = (c * 128 + 64) <= (wq0 + 31);

    unsigned pw[2][16];  // packed bf16 P fragments for both halves
#pragma unroll
    for (int hf = 0; hf < 2; ++hf) {
      if (hf == 0 || act1) {
        const int kb = c * 128 + hf * 64;
        const char* sKb = (const char*)sK[cur] + hf * 8192;

        // ---- S^T = K . Q^T : C[key][q], col=lane&31=q ----
        f32x16 s[2];
        s[0] = (f32x16)0.f;
        s[1] = (f32x16)0.f;
        __builtin_amdgcn_s_setprio(1);
#pragma unroll
        for (int ks = 0; ks < 4; ++ks) {
#pragma unroll
          for (int kc = 0; kc < 2; ++kc) {
            short8 kf = *(const short8*)(sKb + ks * 2048 + kc * 1024 + rdBase);
            s[kc] = MFMA32(kf, qf[ks], s[kc]);
          }
        }
        __builtin_amdgcn_s_setprio(0);

        // ---- causal mask (boundary chunks only; wave-uniform trigger) ----
        if (kb + 63 > wq0) {
#pragma unroll
          for (int kc = 0; kc < 2; ++kc)
#pragma unroll
            for (int r = 0; r < 16; ++r) {
              const int key = kb + kc * 32 + (r & 3) + 8 * (r >> 2) + 4 * hi;
              if (key > qG) s[kc][r] = -110.f;
            }
        }

        // ---- P = 2^(S-8) via fast exp2, then pack to bf16 fragments ----
#pragma unroll
        for (int kc = 0; kc < 2; ++kc)
#pragma unroll
          for (int r = 0; r < 16; ++r)
            s[kc][r] = fexp2m8(s[kc][r]);

#pragma unroll
        for (int ks2 = 0; ks2 < 4; ++ks2) {
          const int kc = ks2 >> 1, rb = (ks2 & 1) * 8;
          unsigned W0 = cvt_pk_bf16(s[kc][rb + 0], s[kc][rb + 1]);
          unsigned W1 = cvt_pk_bf16(s[kc][rb + 2], s[kc][rb + 3]);
          unsigned W2 = cvt_pk_bf16(s[kc][rb + 4], s[kc][rb + 5]);
          unsigned W3 = cvt_pk_bf16(s[kc][rb + 6], s[kc][rb + 7]);
          asm("v_permlane32_swap_b32 %0, %1" : "+v"(W0), "+v"(W2));
          asm("v_permlane32_swap_b32 %0, %1" : "+v"(W1), "+v"(W3));
          pw[hf][ks2 * 4 + 0] = W0;
          pw[hf][ks2 * 4 + 1] = W1;
          pw[hf][ks2 * 4 + 2] = W2;
          pw[hf][ks2 * 4 + 3] = W3;
        }
      }
    }

    __syncthreads();  // drains V(c) + K(c+1) staging (covered by compute)

    // ---- PV both halves from single V buffer; ones-row-MFMA denominator ----
#pragma unroll
    for (int hf = 0; hf < 2; ++hf) {
      if (hf == 0 || act1) {
        const char* sVb = (const char*)sV + hf * 8192;
        __builtin_amdgcn_s_setprio(1);
#pragma unroll
        for (int ks2 = 0; ks2 < 4; ++ks2) {
          union { unsigned w[4]; short8 v; } pb;
          pb.w[0] = pw[hf][ks2 * 4 + 0];
          pb.w[1] = pw[hf][ks2 * 4 + 1];
          pb.w[2] = pw[hf][ks2 * 4 + 2];
          pb.w[3] = pw[hf][ks2 * 4 + 3];
#pragma unroll
          for (int dt = 0; dt < 2; ++dt) {
            short8 vf = *(const short8*)(sVb + ks2 * 2048 + dt * 1024 + rdBase);
            yacc[dt] = MFMA32(vf, pb.v, yacc[dt]);
          }
          lsum = MFMA32(onesf, pb.v, lsum);
        }
        __builtin_amdgcn_s_setprio(0);
      }
    }
    __syncthreads();  // pure LDS reuse fence (nothing in flight)
  }

  // ---- epilogue: y[q][d], q = lane&31, d = dt*32 + (r&3)+8*(r>>2)+4*hi ----
  const float inv = 1.f / lsum[0];
  u16* Yr = Y + (size_t)(bb * 4096 + qt * 128 + wv * 32 + l31) * 768 + hh * 64;
#pragma unroll
  for (int dt = 0; dt < 2; ++dt)
#pragma unroll
    for (int g = 0; g < 4; ++g) {
      u16x4 pk = {f2bf(yacc[dt][g * 4 + 0] * inv), f2bf(yacc[dt][g * 4 + 1] * inv),
                  f2bf(yacc[dt][g * 4 + 2] * inv), f2bf(yacc[dt][g * 4 + 3] * inv)};
      *(u16x4*)(Yr + dt * 32 + g * 8 + hi * 4) = pk;
    }
#undef STAGE_K
#undef STAGE_V
}

// ---------------- host ----------------
extern "C" void kernel_launch(void* const* d_in, const int* in_sizes, int n_in,
                              void* d_out, int out_size, void* d_ws, size_t ws_size,
                              hipStream_t stream) {
  const float* x = (const float*)d_in[0];
  const float* ln1w = (const float*)d_in[1];
  const float* ln1b = (const float*)d_in[2];
  const float* wqkv = (const float*)d_in[3];
  const float* wproj = (const float*)d_in[4];
  const float* bproj = (const float*)d_in[5];
  const float* ln2w = (const float*)d_in[6];
  const float* ln2b = (const float*)d_in[7];
  const float* w1 = (const float*)d_in[8];
  const float* b1 = (const float*)d_in[9];
  const float* w2 = (const float*)d_in[10];
  const float* b2 = (const float*)d_in[11];
  float* out = (float*)d_out;
  char* ws = (char*)d_ws;

  const size_t SZ_ACT = (size_t)8192 * 768 * 2;
  u16* hbuf = (u16*)(ws);
  u16* qb = (u16*)(ws + SZ_ACT);
  u16* kb = (u16*)(ws + 2 * SZ_ACT);
  u16* vT = (u16*)(ws + 3 * SZ_ACT);
  u16* ybuf = (u16*)(ws + 4 * SZ_ACT);
  u16* out1b = (u16*)(ws + 5 * SZ_ACT);  // bf16 residual stream (x + attn)
  char* wsw = ws + 5 * SZ_ACT + (size_t)8192 * 768 * 4;
  u16* wqkvT = (u16*)(wsw);
  u16* wprojT = (u16*)(wsw + 3538944);
  u16* w1T = (u16*)(wsw + 3538944 + 1179648);
  u16* w2T = (u16*)(wsw + 3538944 + 1179648 + 4718592);
  u16* h3 = hbuf;
  u16* h2 = ybuf;

  prep_k<<<15104, 256, 0, stream>>>(wqkv, wproj, w1, w2,
                                    wqkvT, wprojT, w1T, w2T,
                                    x, ln1w, ln1b, hbuf);

  gemm_k<0><<<64 * (2304 / 128), 256, 0, stream>>>(hbuf, wqkvT, 768, 2304,
      nullptr, nullptr, nullptr, nullptr, qb, kb, vT);

  attn_k<<<768, 256, 0, stream>>>(qb, kb, vT, ybuf);

  gemm64_k<0><<<64 * (768 / 64), 256, 0, stream>>>(ybuf, wprojT, 768, 768,
      bproj, x, nullptr, nullptr, out1b);

  ln_k<<<8192, 256, 0, stream>>>(out1b, ln2w, ln2b, h2);

  gemm_k<2><<<64 * (3072 / 128), 256, 0, stream>>>(h2, w1T, 768, 3072,
      b1, nullptr, nullptr, h3, nullptr, nullptr, nullptr);

  gemm64_k<1><<<64 * (768 / 64), 256, 0, stream>>>(h3, w2T, 3072, 768,
      b2, nullptr, out1b, out, nullptr);

  (void)in_sizes; (void)n_in; (void)out_size; (void)ws_size;
}